// Round 9
// baseline (41.908 us; speedup 1.0000x reference)
//
#include <hip/hip_runtime.h>

#define NROW 8192
#define MDIM 128
#define KLAB 16
#define NSLAB 64                     // 8192 / 128 supertile rows
#define NTILE (NSLAB*(NSLAB+1)/2)    // 2080 upper-tri supertiles
#define MARGINP  16.970562748477139f // 1.5 * sqrt(128): margin pre-scaled (defer /sqrt(128))
#define MARGINP2 288.0f              // MARGINP^2 exactly

typedef __attribute__((ext_vector_type(8))) short  s16x8;
typedef __attribute__((ext_vector_type(4))) float  f32x4;

#if __has_builtin(__builtin_amdgcn_sqrtf)
#define FSQRT(x) __builtin_amdgcn_sqrtf(x)
#else
#define FSQRT(x) sqrtf(x)
#endif
#if __has_builtin(__builtin_amdgcn_rcpf)
#define FRCP(x) __builtin_amdgcn_rcpf(x)
#else
#define FRCP(x) (1.0f / (x))
#endif
#if __has_builtin(__builtin_amdgcn_fmed3f)
#define FCLAMP(x) __builtin_amdgcn_fmed3f((x), 0.0f, MARGINP2)
#else
#define FCLAMP(x) fminf(fmaxf((x), 0.0f), MARGINP2)
#endif

__device__ __forceinline__ unsigned short f2bf(float x) {
  unsigned u = __float_as_uint(x);            // RTNE bf16, inputs finite
  return (unsigned short)((u + 0x7FFFu + ((u >> 16) & 1u)) >> 16);
}

// Wave handles 4 rows (16 lanes/row, 8 floats/lane): bf16 convert + sumsq + label mask.
__global__ void prep_kernel(const float* __restrict__ feat, const int* __restrict__ label,
                            unsigned short* __restrict__ fbf, float* __restrict__ sq,
                            int* __restrict__ maskA) {
  int wv = threadIdx.x >> 6, lane = threadIdx.x & 63;
  int sub = lane >> 4, l16 = lane & 15;
  int row = blockIdx.x * 16 + wv * 4 + sub;
  const float* rp = feat + (size_t)row * MDIM + l16 * 8;
  float4 va = *reinterpret_cast<const float4*>(rp);
  float4 vb = *reinterpret_cast<const float4*>(rp + 4);
  s16x8 st;
  st[0]=(short)f2bf(va.x); st[1]=(short)f2bf(va.y); st[2]=(short)f2bf(va.z); st[3]=(short)f2bf(va.w);
  st[4]=(short)f2bf(vb.x); st[5]=(short)f2bf(vb.y); st[6]=(short)f2bf(vb.z); st[7]=(short)f2bf(vb.w);
  *reinterpret_cast<s16x8*>(fbf + (size_t)row * MDIM + l16 * 8) = st;
  float s = va.x*va.x + va.y*va.y + va.z*va.z + va.w*va.w
          + vb.x*vb.x + vb.y*vb.y + vb.z*vb.z + vb.w*vb.w;
  #pragma unroll
  for (int off = 8; off >= 1; off >>= 1) s += __shfl_xor(s, off);   // reduce within 16-lane row group
  int lab = label[((size_t)blockIdx.x * 16 + wv * 4) * KLAB + lane];
  unsigned long long bal = __ballot(lab > 0);
  if (l16 == 0) {
    sq[row]    = s;
    maskA[row] = (int)(unsigned)((bal >> (sub * 16)) & 0xFFFFull);
  }
}

// Block = 8 waves = one 128x128 supertile (bi<=bj). Slabs staged in LDS (XOR-swizzled).
// Wave wv owns i-rows [wv*16, +16). js loop split into 2 groups of {2x(read+MFMA)} then
// {2x epilogue} so 16 independent sqrt/rcp chains per epilogue phase fill latency bubbles.
// mfma_f32_16x16x32_bf16 layout as verified in round 2 (absmax == 0).
__global__ __launch_bounds__(512, 2) void pair_main(
    const unsigned short* __restrict__ fbf, const float* __restrict__ sq,
    const int* __restrict__ maskA, float* __restrict__ part) {
  __shared__ char smem[65536];            // A slab [0,32K), B slab [32K,64K)
  __shared__ float bsum[8];

  int bi = 0, rem = blockIdx.x;
  while (rem >= NSLAB - bi) { rem -= NSLAB - bi; bi++; }
  int bj = bi + rem;
  bool diag = (bi == bj);

  int wv = threadIdx.x >> 6, lane = threadIdx.x & 63;
  int l15 = lane & 15, lg = lane >> 4;

  // ---- stage both slabs: coalesced 16B/lane global loads -> swizzled ds_write_b128 ----
  {
    const char* gA = (const char*)(fbf + (size_t)bi * 128 * MDIM);
    const char* gB = (const char*)(fbf + (size_t)bj * 128 * MDIM);
    int sub = lane >> 4, c = lane & 15;
    #pragma unroll
    for (int t = 0; t < 4; t++) {
      int lr = wv * 16 + t * 4 + sub;                 // local row 0..127
      s16x8 va = *reinterpret_cast<const s16x8*>(gA + lr * 256 + c * 16);
      s16x8 vb = *reinterpret_cast<const s16x8*>(gB + lr * 256 + c * 16);
      int wc = c ^ (lr & 7);                          // XOR swizzle on 16B chunk index
      *reinterpret_cast<s16x8*>(smem + lr * 256 + wc * 16) = va;
      *reinterpret_cast<s16x8*>(smem + 32768 + lr * 256 + wc * 16) = vb;
    }
  }

  // ---- metadata (hoisted; from L2-resident 32KB arrays) ----
  float sqi[4]; int mi[4];
  #pragma unroll
  for (int r = 0; r < 4; r++) {
    int ir = bi * 128 + wv * 16 + lg * 4 + r;         // C/D row = lg*4 + r
    sqi[r] = sq[ir]; mi[r] = maskA[ir];
  }
  float sqj[4][2]; int mj[4][2];
  #pragma unroll
  for (int js = 0; js < 4; js++)
    #pragma unroll
    for (int fj = 0; fj < 2; fj++) {
      int jr = bj * 128 + js * 32 + fj * 16 + l15;    // C/D col = l15
      sqj[js][fj] = sq[jr]; mj[js][fj] = maskA[jr];
    }

  __syncthreads();

  // ---- A fragments for this wave's 16 rows, whole K=128 (16 VGPR) ----
  s16x8 af[4];
  #pragma unroll
  for (int ks = 0; ks < 4; ks++) {
    int lr = wv * 16 + l15;
    int rc = (ks * 4 + lg) ^ (lr & 7);
    af[ks] = *reinterpret_cast<const s16x8*>(smem + lr * 256 + rc * 16);
  }

  float sum = 0.0f;

  #pragma unroll
  for (int g = 0; g < 2; g++) {
    f32x4 acc[2][2];                    // [js-in-group][fj]
    // ---- phase 1: read B + MFMA for both js of this group ----
    #pragma unroll
    for (int q = 0; q < 2; q++) {
      int js = g * 2 + q;
      s16x8 B[2][4];
      #pragma unroll
      for (int fj = 0; fj < 2; fj++)
        #pragma unroll
        for (int ks = 0; ks < 4; ks++) {
          int lr = js * 32 + fj * 16 + l15;
          int rc = (ks * 4 + lg) ^ (lr & 7);
          B[fj][ks] = *reinterpret_cast<const s16x8*>(smem + 32768 + lr * 256 + rc * 16);
        }
      acc[q][0] = (f32x4){0.f,0.f,0.f,0.f}; acc[q][1] = (f32x4){0.f,0.f,0.f,0.f};
      #pragma unroll
      for (int ks = 0; ks < 4; ks++)
        #pragma unroll
        for (int fj = 0; fj < 2; fj++)
          acc[q][fj] = __builtin_amdgcn_mfma_f32_16x16x32_bf16(af[ks], B[fj][ks], acc[q][fj], 0, 0, 0);
    }
    // ---- phase 2: batched epilogue (16 independent chains) ----
    #pragma unroll
    for (int q = 0; q < 2; q++) {
      int js = g * 2 + q;
      #pragma unroll
      for (int fj = 0; fj < 2; fj++)
        #pragma unroll
        for (int r = 0; r < 4; r++) {
          float g2  = acc[q][fj][r];
          float d2 = fmaf(-2.0f, g2, sqi[r] + sqj[js][fj]);
          float t  = FSQRT(FCLAMP(d2));
          int inter = __popc(mi[r] & mj[js][fj]);
          int uni   = __popc(mi[r] | mj[js][fj]);
          float w = (float)inter * FRCP((float)uni);
          w = (inter == 0) ? -1.0f : w;
          if (diag) {
            int il = wv * 16 + lg * 4 + r;
            int jl = js * 32 + fj * 16 + l15;
            w *= (jl > il) ? 2.0f : ((jl == il) ? 1.0f : 0.0f);
          }
          sum = fmaf(w, t, sum);
        }
    }
  }

  #pragma unroll
  for (int off = 32; off >= 1; off >>= 1) sum += __shfl_xor(sum, off);
  if (lane == 0) bsum[wv] = sum;
  __syncthreads();
  if (threadIdx.x == 0) {
    float s = 0.f;
    #pragma unroll
    for (int w = 0; w < 8; w++) s += bsum[w];
    part[blockIdx.x] = diag ? s : 2.0f * s;   // one plain store per block
  }
}

// Single block: sum 2080 partials (double accum) + apply deferred scales.
__global__ void reduce_kernel(const float* __restrict__ part, float* __restrict__ out) {
  int tid = threadIdx.x;
  double s = 0.0;
  for (int i = tid; i < NTILE; i += 256) s += (double)part[i];
  #pragma unroll
  for (int off = 32; off >= 1; off >>= 1) s += __shfl_xor(s, off);
  __shared__ double wsum[4];
  int wv = tid >> 6, lane = tid & 63;
  if (lane == 0) wsum[wv] = s;
  __syncthreads();
  if (tid == 0) {
    double t = wsum[0] + wsum[1] + wsum[2] + wsum[3];
    // undo deferred scales: /sqrt(128) and /n^2
    out[0] = (float)(t * (1.0 / (11.313708498984760 * 67108864.0)));
  }
}

extern "C" void kernel_launch(void* const* d_in, const int* in_sizes, int n_in,
                              void* d_out, int out_size, void* d_ws, size_t ws_size,
                              hipStream_t stream) {
  const float* feat  = (const float*)d_in[0];
  const int*   label = (const int*)d_in[1];
  char* ws = (char*)d_ws;
  float* part           = (float*)ws;                           // 2080 floats (8448 B reserved)
  float* sq             = (float*)(ws + 8448);                  // 32 KB
  int*   maskA          = (int*)(ws + 8448 + 32768);            // 32 KB
  unsigned short* fbf   = (unsigned short*)(ws + 8448 + 65536); // 2 MB bf16 feature
  float* out = (float*)d_out;

  prep_kernel<<<NROW / 16, 256, 0, stream>>>(feat, label, fbf, sq, maskA);
  pair_main<<<NTILE, 512, 0, stream>>>(fbf, sq, maskA, part);
  reduce_kernel<<<1, 256, 0, stream>>>(part, out);
}

// Round 10
// 40.115 us; speedup vs baseline: 1.0447x; 1.0447x over previous
//
#include <hip/hip_runtime.h>

#define NROW 8192
#define MDIM 128
#define KLAB 16
#define NSLAB 64                     // 8192 / 128 supertile rows
#define NTILE (NSLAB*(NSLAB+1)/2)    // 2080 upper-tri supertiles
#define MARGINP  16.970562748477139f // 1.5 * sqrt(128): margin pre-scaled (defer /sqrt(128))
#define MARGINP2 288.0f              // MARGINP^2 exactly

typedef __attribute__((ext_vector_type(8))) short  s16x8;
typedef __attribute__((ext_vector_type(4))) float  f32x4;

#if __has_builtin(__builtin_amdgcn_sqrtf)
#define FSQRT(x) __builtin_amdgcn_sqrtf(x)
#else
#define FSQRT(x) sqrtf(x)
#endif
#if __has_builtin(__builtin_amdgcn_rcpf)
#define FRCP(x) __builtin_amdgcn_rcpf(x)
#else
#define FRCP(x) (1.0f / (x))
#endif
#if __has_builtin(__builtin_amdgcn_fmed3f)
#define FCLAMP(x) __builtin_amdgcn_fmed3f((x), 0.0f, MARGINP2)
#else
#define FCLAMP(x) fminf(fmaxf((x), 0.0f), MARGINP2)
#endif

__device__ __forceinline__ unsigned short f2bf(float x) {
  unsigned u = __float_as_uint(x);            // RTNE bf16, inputs finite
  return (unsigned short)((u + 0x7FFFu + ((u >> 16) & 1u)) >> 16);
}

// Wave handles 4 rows (16 lanes/row, 8 floats/lane): bf16 convert + sumsq + label mask.
__global__ void prep_kernel(const float* __restrict__ feat, const int* __restrict__ label,
                            unsigned short* __restrict__ fbf, float* __restrict__ sq,
                            int* __restrict__ maskA) {
  int wv = threadIdx.x >> 6, lane = threadIdx.x & 63;
  int sub = lane >> 4, l16 = lane & 15;
  int row = blockIdx.x * 16 + wv * 4 + sub;
  const float* rp = feat + (size_t)row * MDIM + l16 * 8;
  float4 va = *reinterpret_cast<const float4*>(rp);
  float4 vb = *reinterpret_cast<const float4*>(rp + 4);
  s16x8 st;
  st[0]=(short)f2bf(va.x); st[1]=(short)f2bf(va.y); st[2]=(short)f2bf(va.z); st[3]=(short)f2bf(va.w);
  st[4]=(short)f2bf(vb.x); st[5]=(short)f2bf(vb.y); st[6]=(short)f2bf(vb.z); st[7]=(short)f2bf(vb.w);
  *reinterpret_cast<s16x8*>(fbf + (size_t)row * MDIM + l16 * 8) = st;
  float s = va.x*va.x + va.y*va.y + va.z*va.z + va.w*va.w
          + vb.x*vb.x + vb.y*vb.y + vb.z*vb.z + vb.w*vb.w;
  #pragma unroll
  for (int off = 8; off >= 1; off >>= 1) s += __shfl_xor(s, off);   // reduce within 16-lane row group
  int lab = label[((size_t)blockIdx.x * 16 + wv * 4) * KLAB + lane];
  unsigned long long bal = __ballot(lab > 0);
  if (l16 == 0) {
    sq[row]    = s;
    maskA[row] = (int)(unsigned)((bal >> (sub * 16)) & 0xFFFFull);
  }
}

// Block = 8 waves (4x2 grid) = one 128x128 supertile (bi<=bj). Slabs in LDS, XOR-swizzled.
// Wave (wr,wc) owns rows [wr*32,+32) x cols [wc*64,+64): LDS reads/wave = A 8 + B 16
// (was 4+32 with the 1D 16x128 mapping — LDS port was the bottleneck pipe).
// mfma_f32_16x16x32_bf16 layout as verified in round 2 (absmax == 0).
__global__ __launch_bounds__(512, 2) void pair_main(
    const unsigned short* __restrict__ fbf, const float* __restrict__ sq,
    const int* __restrict__ maskA, float* __restrict__ part) {
  __shared__ char smem[65536];            // A slab [0,32K), B slab [32K,64K)
  __shared__ float bsum[8];

  int bi = 0, rem = blockIdx.x;
  while (rem >= NSLAB - bi) { rem -= NSLAB - bi; bi++; }
  int bj = bi + rem;
  bool diag = (bi == bj);

  int wv = threadIdx.x >> 6, lane = threadIdx.x & 63;
  int l15 = lane & 15, lg = lane >> 4;
  int wr = wv >> 1, wc = wv & 1;          // 4x2 wave grid

  // ---- stage both slabs: coalesced 16B/lane global loads -> swizzled ds_write_b128 ----
  {
    const char* gA = (const char*)(fbf + (size_t)bi * 128 * MDIM);
    const char* gB = (const char*)(fbf + (size_t)bj * 128 * MDIM);
    int sub = lane >> 4, c = lane & 15;
    #pragma unroll
    for (int t = 0; t < 4; t++) {
      int lr = wv * 16 + t * 4 + sub;                 // local row 0..127
      s16x8 va = *reinterpret_cast<const s16x8*>(gA + lr * 256 + c * 16);
      s16x8 vb = *reinterpret_cast<const s16x8*>(gB + lr * 256 + c * 16);
      int wck = c ^ (lr & 7);                         // XOR swizzle on 16B chunk index
      *reinterpret_cast<s16x8*>(smem + lr * 256 + wck * 16) = va;
      *reinterpret_cast<s16x8*>(smem + 32768 + lr * 256 + wck * 16) = vb;
    }
  }

  // ---- metadata (hoisted; from L2-resident 32KB arrays) ----
  float sqi[2][4]; int mi[2][4];
  #pragma unroll
  for (int fi = 0; fi < 2; fi++)
    #pragma unroll
    for (int r = 0; r < 4; r++) {
      int ir = bi * 128 + wr * 32 + fi * 16 + lg * 4 + r;   // C/D row = lg*4 + r
      sqi[fi][r] = sq[ir]; mi[fi][r] = maskA[ir];
    }
  float sqj[4]; int mj[4];
  #pragma unroll
  for (int fj = 0; fj < 4; fj++) {
    int jr = bj * 128 + wc * 64 + fj * 16 + l15;            // C/D col = l15
    sqj[fj] = sq[jr]; mj[fj] = maskA[jr];
  }

  __syncthreads();

  // ---- A fragments: this wave's 32 rows, whole K=128 (32 VGPR) ----
  s16x8 af[2][4];
  #pragma unroll
  for (int fi = 0; fi < 2; fi++)
    #pragma unroll
    for (int ks = 0; ks < 4; ks++) {
      int lr = wr * 32 + fi * 16 + l15;
      int rc = (ks * 4 + lg) ^ (lr & 7);
      af[fi][ks] = *reinterpret_cast<const s16x8*>(smem + lr * 256 + rc * 16);
    }

  float sum = 0.0f;

  #pragma unroll
  for (int fj = 0; fj < 4; fj++) {
    // B fragments for this 16-col subtile (16 VGPR live)
    s16x8 B[4];
    #pragma unroll
    for (int ks = 0; ks < 4; ks++) {
      int lr = wc * 64 + fj * 16 + l15;
      int rc = (ks * 4 + lg) ^ (lr & 7);
      B[ks] = *reinterpret_cast<const s16x8*>(smem + 32768 + lr * 256 + rc * 16);
    }

    f32x4 acc[2];
    acc[0] = (f32x4){0.f,0.f,0.f,0.f}; acc[1] = (f32x4){0.f,0.f,0.f,0.f};
    #pragma unroll
    for (int ks = 0; ks < 4; ks++)
      #pragma unroll
      for (int fi = 0; fi < 2; fi++)
        acc[fi] = __builtin_amdgcn_mfma_f32_16x16x32_bf16(af[fi][ks], B[ks], acc[fi], 0, 0, 0);

    #pragma unroll
    for (int fi = 0; fi < 2; fi++)
      #pragma unroll
      for (int r = 0; r < 4; r++) {
        float g  = acc[fi][r];
        float d2 = fmaf(-2.0f, g, sqi[fi][r] + sqj[fj]);
        float t  = FSQRT(FCLAMP(d2));
        int inter = __popc(mi[fi][r] & mj[fj]);
        int uni   = __popc(mi[fi][r] | mj[fj]);
        float w = (float)inter * FRCP((float)uni);
        w = (inter == 0) ? -1.0f : w;
        if (diag) {
          int il = wr * 32 + fi * 16 + lg * 4 + r;
          int jl = wc * 64 + fj * 16 + l15;
          w *= (jl > il) ? 2.0f : ((jl == il) ? 1.0f : 0.0f);
        }
        sum = fmaf(w, t, sum);
      }
  }

  #pragma unroll
  for (int off = 32; off >= 1; off >>= 1) sum += __shfl_xor(sum, off);
  if (lane == 0) bsum[wv] = sum;
  __syncthreads();
  if (threadIdx.x == 0) {
    float s = 0.f;
    #pragma unroll
    for (int w = 0; w < 8; w++) s += bsum[w];
    part[blockIdx.x] = diag ? s : 2.0f * s;   // one plain store per block
  }
}

// Single block: sum 2080 partials (double accum) + apply deferred scales.
__global__ void reduce_kernel(const float* __restrict__ part, float* __restrict__ out) {
  int tid = threadIdx.x;
  double s = 0.0;
  for (int i = tid; i < NTILE; i += 256) s += (double)part[i];
  #pragma unroll
  for (int off = 32; off >= 1; off >>= 1) s += __shfl_xor(s, off);
  __shared__ double wsum[4];
  int wv = tid >> 6, lane = tid & 63;
  if (lane == 0) wsum[wv] = s;
  __syncthreads();
  if (tid == 0) {
    double t = wsum[0] + wsum[1] + wsum[2] + wsum[3];
    // undo deferred scales: /sqrt(128) and /n^2
    out[0] = (float)(t * (1.0 / (11.313708498984760 * 67108864.0)));
  }
}

extern "C" void kernel_launch(void* const* d_in, const int* in_sizes, int n_in,
                              void* d_out, int out_size, void* d_ws, size_t ws_size,
                              hipStream_t stream) {
  const float* feat  = (const float*)d_in[0];
  const int*   label = (const int*)d_in[1];
  char* ws = (char*)d_ws;
  float* part           = (float*)ws;                           // 2080 floats (8448 B reserved)
  float* sq             = (float*)(ws + 8448);                  // 32 KB
  int*   maskA          = (int*)(ws + 8448 + 32768);            // 32 KB
  unsigned short* fbf   = (unsigned short*)(ws + 8448 + 65536); // 2 MB bf16 feature
  float* out = (float*)d_out;

  prep_kernel<<<NROW / 16, 256, 0, stream>>>(feat, label, fbf, sq, maskA);
  pair_main<<<NTILE, 512, 0, stream>>>(fbf, sq, maskA, part);
  reduce_kernel<<<1, 256, 0, stream>>>(part, out);
}